// Round 8
// baseline (87.106 us; speedup 1.0000x reference)
//
#include <hip/hip_runtime.h>
#include <math.h>

// DETR loss with per-batch Hungarian matching (Jonker-Volgenant, exact).
//
// One block = one wave (64 lanes) per batch; lane t owns cost column t+1
// (pred t) and compacted row t+1. All matcher state in registers. Row-
// reduction init (u[i]=rowmin, v=0; rows claim argmin columns greedily --
// valid rectangular dual, verified round 7). Dijkstra phases only for
// contested rows.
//
// Round 8 (bit-identical matcher decisions, faster plumbing):
//  - DPP min chain with old=x -> GCNDPPCombine folds mov_dpp+min into
//    v_min_u32_dpp (one instr/step).
//  - Cs stored as f64 in LDS (no per-iteration cvt_f64_f32).
//  - delta hi-word reconstructed from the argmin key on SALU (exact unmap);
//    only the lo-word is readlaned.
//  - cost build reads gt rows via readlane from per-lane registers (row
//    index from SALU bit-iteration of the validity mask) -- no LDS chain.
//  - next-phase C-head prefetched at phase start (latency hidden).
//  - final mean fused into the match kernel: last block (device-scope
//    atomic counter, AGENT-scope stores/loads for cross-XCD coherence)
//    reduces the per-batch losses. Counter zeroed via hipMemsetAsync.

#define SS 64
#define LDS_FENCE() asm volatile("s_waitcnt lgkmcnt(0)" ::: "memory")

__device__ __forceinline__ int rlane_i(int x, int lane) {
    return __builtin_amdgcn_readlane(x, lane);
}
__device__ __forceinline__ double rlane_d(double x, int lane) {
    return __hiloint2double(rlane_i(__double2hiint(x), lane),
                            rlane_i(__double2loint(x), lane));
}

// One min-reduce step; old = x makes invalid-source lanes the identity,
// enabling the mov_dpp+min -> v_min_u32_dpp fold.
template<int CTRL>
__device__ __forceinline__ unsigned mstep(unsigned x) {
    const unsigned y = (unsigned)__builtin_amdgcn_update_dpp(
        (int)x, (int)x, CTRL, 0xF, 0xF, false);
    return x < y ? x : y;
}
// After this, lane 63 holds the u32 min over all 64 lanes.
__device__ __forceinline__ unsigned wave_min_u32_to63(unsigned x) {
    x = mstep<0x111>(x);  // row_shr:1
    x = mstep<0x112>(x);  // row_shr:2
    x = mstep<0x114>(x);  // row_shr:4
    x = mstep<0x118>(x);  // row_shr:8
    x = mstep<0x142>(x);  // row_bcast15
    x = mstep<0x143>(x);  // row_bcast31
    return x;
}

__global__ __launch_bounds__(64) void detr_match_loss_kernel(
    const float* __restrict__ pred_strokes,   // [B,64,10]
    const float* __restrict__ pred_validity,  // [B,64,1]
    const float* __restrict__ targets,        // [B,64,11]
    double* __restrict__ loss_ws,             // [B]
    unsigned* __restrict__ counter,           // zeroed each launch
    float* __restrict__ out, int B)
{
    const int b = blockIdx.x;
    const int t = threadIdx.x;   // lane; owns column j = t+1, compacted row t+1
    const float* ps = pred_strokes  + (size_t)b * SS * 10;
    const float* pv = pred_validity + (size_t)b * SS;
    const float* tg = targets      + (size_t)b * SS * 11;

    __shared__ double Cs[SS * SS];     // cost, f64, [compacted row][64]
    __shared__ int    col4row[SS];     // compacted gt-row -> pred col

    // --- per-lane gt row (slot t) in registers ---
    float tgv[11];
#pragma unroll
    for (int k = 0; k < 11; ++k) tgv[k] = tg[t * 11 + k];
    const float gv    = tgv[10];
    const bool  valid = gv > 0.5f;
    const unsigned long long vmask = __ballot(valid);
    const int ng = __popcll(vmask);

    // --- BCE term (slot t) ---
    double bterm;
    {
        const float pvv = pv[t];
        const float lp  = fmaxf(logf(pvv), -100.0f);
        const float l1p = fmaxf(logf(1.0f - pvv), -100.0f);
        bterm = -((double)gv * (double)lp + (double)(1.0f - gv) * (double)l1p);
    }

    double csum = 0.0, wsum = 0.0;

    if (ng > 0) {
        // --- cost build + fused row-reduction claims (no LDS reads) ---
        float pr[10];
#pragma unroll
        for (int k = 0; k < 10; ++k) pr[k] = ps[t * 10 + k];

        double u_reg = 0.0;                 // u[t+1] (lane t = compacted row t+1)
        int    p_j   = 0;                   // p[t+1]: matched compacted row
        unsigned long long colclaim = 0ull; // claimed-column mask (uniform)
        unsigned long long freerows = 0ull; // contested-row mask (uniform)
        unsigned long long vm = vmask;

        for (int i = 0; i < ng; ++i) {
            const int vrow = __ffsll(vm) - 1;  // original slot of row i (SALU)
            vm &= vm - 1;
            float g[10];
#pragma unroll
            for (int k = 0; k < 10; ++k)
                g[k] = __uint_as_float(
                    (unsigned)rlane_i(__float_as_int(tgv[k]), vrow));
            float d[10];
#pragma unroll
            for (int k = 0; k < 10; ++k) d[k] = fabsf(pr[k] - g[k]);
            const float cs = ((d[0] + d[1]) + (d[2] + d[3]))
                           + ((d[4] + d[5]) + (d[6] + d[7]));   // numpy tree
            const float wd = d[8] + d[9];
            float c;
            {
#pragma clang fp contract(off)
                c = 5.0f * cs + wd;                // mul-then-add, no fma
            }
            Cs[i * SS + t] = (double)c;

            // row min/argmin (c >= 0: f32 bits order-preserving as u32)
            const unsigned key = __float_as_uint(c);
            const unsigned mst = (unsigned)rlane_i(
                (int)wave_min_u32_to63(key), 63);
            const unsigned long long rbal = __ballot(key == mst);
            const int jstar = __ffsll(rbal) - 1;   // 0-based argmin column
            if (t == i) u_reg = (double)__uint_as_float(mst); // u[i+1]=rowmin
            if (!((colclaim >> jstar) & 1ull)) {
                colclaim |= 1ull << jstar;
                if (t == jstar) p_j = i + 1;       // tight edge (cur == 0)
            } else {
                freerows |= 1ull << i;             // contested -> Dijkstra
            }
        }

        // --- Dijkstra phases for contested rows; v starts at 0 ---
        double v_j = 0.0;   // v[t+1]
        int nr0 = freerows ? (__ffsll(freerows) - 1) : -1;
        double Chead = (nr0 >= 0) ? Cs[nr0 * SS + t] : 0.0;

        while (freerows) {
            const int r0 = nr0;                    // 0-based root row, uniform
            freerows &= freerows - 1;
            nr0 = freerows ? (__ffsll(freerows) - 1) : -1;
            const int i = r0 + 1;

            double minv_j   = __builtin_inf();
            int    way_j    = 0;
            bool   used_j   = false;
            bool   row_used = (t == r0);           // p[0] = i
            double u0       = rlane_d(u_reg, r0);  // u[i] = rowmin_i
            int    j0       = 0;
            double Cval     = Chead;

            // prefetch NEXT phase's head now; consumed after this phase
            const double Chead_next = (nr0 >= 0) ? Cs[nr0 * SS + t] : 0.0;

            for (;;) {
                used_j = used_j || (t + 1 == j0);
                const double cur = (Cval - u0) - v_j;
                if (!used_j && cur < minv_j) { minv_j = cur; way_j = j0; }

                // wave argmin: order-preserving u32 map of the f64 hi-word
                const int      hi  = __double2hiint(minv_j);
                const int      s31 = hi >> 31;
                unsigned key = (unsigned)(hi ^ (s31 | (int)0x80000000));
                if (used_j) key = 0xFFFFFFFFu;
                const unsigned hstar = (unsigned)rlane_i(
                    (int)wave_min_u32_to63(key), 63);
                unsigned long long bal = __ballot(key == hstar);
                int j1 = __ffsll(bal);                       // col = lane+1
                int i1 = rlane_i(p_j, j1 - 1);               // p[j1]

                // speculative prefetch of next C entry
                double C_next = 0.0;
                if (i1 != 0) C_next = Cs[(i1 - 1) * SS + t];

                if (__popcll(bal) > 1) {   // rare: resolve lo32 among ties
                    // tied lanes share the sign bit -> sign-mapped lo32
                    // comparison == full f64 comparison
                    const unsigned lraw = (unsigned)__double2loint(minv_j);
                    const unsigned lo   = (key == hstar)
                                        ? (s31 ? ~lraw : lraw) : 0xFFFFFFFFu;
                    const unsigned lstar = (unsigned)rlane_i(
                        (int)wave_min_u32_to63(lo), 63);
                    bal = __ballot(key == hstar && lo == lstar);
                    j1  = __ffsll(bal);
                    i1  = rlane_i(p_j, j1 - 1);
                    if (i1 != 0) C_next = Cs[(i1 - 1) * SS + t];
                }

                // delta: hi from exact key unmap (SALU), lo readlaned
                const int hmin = (hstar & 0x80000000u)
                               ? (int)(hstar & 0x7FFFFFFFu) : (int)~hstar;
                const int lmin = rlane_i(__double2loint(minv_j), j1 - 1);
                const double delta  = __hiloint2double(hmin, lmin);
                const double u_next = (i1 != 0) ? rlane_d(u_reg, i1 - 1) : 0.0;
                // (row i1 not yet row_used this iteration, so u_next is
                //  unaffected by the predicated add below.)

                // dual/minv updates
                if (row_used) u_reg += delta;     // u[p[used]] += delta
                if (used_j)   v_j   -= delta;     // v[used]    -= delta
                else          minv_j -= delta;    // minv[unused] -= delta
                row_used = row_used || (t == i1 - 1);

                j0 = j1;
                if (i1 == 0) break;               // reached unmatched column
                u0 = u_next; Cval = C_next;
            }

            // --- augment along way[] (readlane pointer chase, short) ---
            int jj = j0;
            while (jj != 0) {
                const int jp   = rlane_i(way_j, jj - 1);
                const int pnew = (jp == 0) ? i : rlane_i(p_j, jp - 1);
                if (t == jj - 1) p_j = pnew;
                jj = jp;
            }
            Chead = Chead_next;
        }

        // --- extract assignment ---
        if (p_j > 0) col4row[p_j - 1] = t;
        LDS_FENCE();

        // --- matched L1 sums: lane s handles its own valid gt slot ---
        if (valid) {
            const int r = __popcll(vmask & ((1ull << t) - 1ull)); // compacted
            const float* mp = ps + col4row[r] * 10;
#pragma unroll
            for (int k = 0; k < 8; ++k) csum += (double)fabsf(mp[k] - tgv[k]);
            wsum = (double)fabsf(mp[8] - tgv[8]) + (double)fabsf(mp[9] - tgv[9]);
        }
    }

    // --- wave reductions (cold path) ---
    double s0 = csum, s1 = wsum, s2 = bterm;
#pragma unroll
    for (int off = 1; off < 64; off <<= 1) {
        s0 += __shfl_xor(s0, off, 64);
        s1 += __shfl_xor(s1, off, 64);
        s2 += __shfl_xor(s2, off, 64);
    }

    unsigned prev = 0;
    if (t == 0) {
        const double bce = s2 / 64.0;
        const double loss = (ng > 0)
            ? 5.0 * (s0 / ((double)ng * 8.0)) + (s1 / ((double)ng * 2.0)) + bce
            : bce;
        __hip_atomic_store(&loss_ws[b], loss,
                           __ATOMIC_RELEASE, __HIP_MEMORY_SCOPE_AGENT);
        prev = __hip_atomic_fetch_add(counter, 1u,
                                      __ATOMIC_ACQ_REL, __HIP_MEMORY_SCOPE_AGENT);
    }
    prev = (unsigned)rlane_i((int)prev, 0);

    if (prev == (unsigned)(B - 1)) {   // last block: final mean
        double x = 0.0;
        for (int idx = t; idx < B; idx += SS)
            x += __hip_atomic_load(&loss_ws[idx],
                                   __ATOMIC_RELAXED, __HIP_MEMORY_SCOPE_AGENT);
#pragma unroll
        for (int off = 1; off < 64; off <<= 1) x += __shfl_xor(x, off, 64);
        if (t == 0) out[0] = (float)(x / (double)B);
    }
}

extern "C" void kernel_launch(void* const* d_in, const int* in_sizes, int n_in,
                              void* d_out, int out_size, void* d_ws, size_t ws_size,
                              hipStream_t stream) {
    const float* ps = (const float*)d_in[0];
    const float* pv = (const float*)d_in[1];
    const float* tg = (const float*)d_in[2];
    float* out = (float*)d_out;
    const int B = in_sizes[0] / (SS * 10);

    double*   ws  = (double*)d_ws;
    unsigned* cnt = (unsigned*)((char*)d_ws + (size_t)B * sizeof(double));
    hipMemsetAsync(cnt, 0, sizeof(unsigned), stream);

    detr_match_loss_kernel<<<B, SS, 0, stream>>>(ps, pv, tg, ws, cnt, out, B);
}